// Round 1
// baseline (35031.656 us; speedup 1.0000x reference)
//
#include <hip/hip_runtime.h>
#include <math.h>

// GRU dynamics: B=2048, LATENT=256, HIDDEN=512, N_STEPS=100 (fixed by problem).
// One workgroup owns ROWS batch rows for the entire rollout (recurrence is
// row-independent -> no grid sync). x (=p,lat,lon) and h live in LDS.
#define B_SZ   2048
#define LAT    256
#define KIN    258      // LATENT + 2
#define HID    512
#define ROWS   8
#define NTHR   512
#define NBLK   (B_SZ / ROWS)   // 256 workgroups -> 1 per CU

__device__ __forceinline__ float sigm(float x) {
    return 1.0f / (1.0f + __expf(-x));
}
__device__ __forceinline__ float tanh_f(float x) {
    float e = __expf(-2.0f * fabsf(x));
    float t = (1.0f - e) / (1.0f + e);
    return copysignf(t, x);
}

__global__ __launch_bounds__(NTHR) void gru_roll_kernel(
    const float* __restrict__ p0, const float* __restrict__ latv,
    const float* __restrict__ lonv, const float* __restrict__ W_ih,
    const float* __restrict__ W_hh, const float* __restrict__ b_ih,
    const float* __restrict__ b_hh, const float* __restrict__ W_proj,
    const float* __restrict__ b_proj, float* __restrict__ out, int n_steps)
{
    __shared__ float x_s[ROWS][KIN];        // [p | lat | lon] per row
    __shared__ float h_s[2][ROWS][HID];     // double-buffered hidden state

    const int t    = threadIdx.x;
    const int row0 = blockIdx.x * ROWS;

    const int o  = t & (LAT - 1);   // latent output index for proj phase
    const int rh = t >> 8;          // 0/1: which half of the rows

    // ---- init: x = p0, out[step 0] = p0, h = 0 ----
    #pragma unroll
    for (int ri = 0; ri < ROWS / 2; ++ri) {
        int r = rh * (ROWS / 2) + ri;
        float v = p0[(size_t)(row0 + r) * LAT + o];
        x_s[r][o] = v;
        out[(size_t)(row0 + r) * LAT + o] = v;
    }
    if (t < ROWS) {
        x_s[t][LAT]     = latv[row0 + t];
        x_s[t][LAT + 1] = lonv[row0 + t];
    }
    for (int i = t; i < ROWS * HID; i += NTHR) ((float*)h_s[0])[i] = 0.0f;

    // ---- hoisted per-thread constants ----
    const int j = t;  // hidden unit 0..511
    const float bI0 = b_ih[j], bI1 = b_ih[HID + j], bI2 = b_ih[2 * HID + j];
    const float bH0 = b_hh[j], bH1 = b_hh[HID + j], bH2 = b_hh[2 * HID + j];
    const float2* wi0 = (const float2*)(W_ih + (size_t)j * KIN);
    const float2* wi1 = (const float2*)(W_ih + (size_t)(HID + j) * KIN);
    const float2* wi2 = (const float2*)(W_ih + (size_t)(2 * HID + j) * KIN);
    const float4* wh0 = (const float4*)(W_hh + (size_t)j * HID);
    const float4* wh1 = (const float4*)(W_hh + (size_t)(HID + j) * HID);
    const float4* wh2 = (const float4*)(W_hh + (size_t)(2 * HID + j) * HID);
    const float4* wp  = (const float4*)(W_proj + (size_t)o * HID);
    const float   bp  = b_proj[o];

    __syncthreads();

    int cur = 0;
    for (int s = 0; s < n_steps; ++s) {
        // ---------- phase A: gates for hidden unit j, all ROWS rows ----------
        float aI0[ROWS], aI1[ROWS], aI2[ROWS];
        #pragma unroll
        for (int r = 0; r < ROWS; ++r) { aI0[r] = bI0; aI1[r] = bI1; aI2[r] = bI2; }
        for (int k = 0; k < KIN / 2; ++k) {
            float2 w0 = wi0[k], w1 = wi1[k], w2 = wi2[k];
            #pragma unroll
            for (int r = 0; r < ROWS; ++r) {
                float2 xv = *(const float2*)&x_s[r][2 * k];   // broadcast
                aI0[r] = fmaf(w0.x, xv.x, aI0[r]); aI0[r] = fmaf(w0.y, xv.y, aI0[r]);
                aI1[r] = fmaf(w1.x, xv.x, aI1[r]); aI1[r] = fmaf(w1.y, xv.y, aI1[r]);
                aI2[r] = fmaf(w2.x, xv.x, aI2[r]); aI2[r] = fmaf(w2.y, xv.y, aI2[r]);
            }
        }
        float aH0[ROWS], aH1[ROWS], aH2[ROWS];
        #pragma unroll
        for (int r = 0; r < ROWS; ++r) { aH0[r] = bH0; aH1[r] = bH1; aH2[r] = bH2; }
        for (int k = 0; k < HID / 4; ++k) {
            float4 w0 = wh0[k], w1 = wh1[k], w2 = wh2[k];
            #pragma unroll
            for (int r = 0; r < ROWS; ++r) {
                float4 hv = *(const float4*)&h_s[cur][r][4 * k];  // broadcast
                aH0[r] = fmaf(w0.x, hv.x, aH0[r]); aH0[r] = fmaf(w0.y, hv.y, aH0[r]);
                aH0[r] = fmaf(w0.z, hv.z, aH0[r]); aH0[r] = fmaf(w0.w, hv.w, aH0[r]);
                aH1[r] = fmaf(w1.x, hv.x, aH1[r]); aH1[r] = fmaf(w1.y, hv.y, aH1[r]);
                aH1[r] = fmaf(w1.z, hv.z, aH1[r]); aH1[r] = fmaf(w1.w, hv.w, aH1[r]);
                aH2[r] = fmaf(w2.x, hv.x, aH2[r]); aH2[r] = fmaf(w2.y, hv.y, aH2[r]);
                aH2[r] = fmaf(w2.z, hv.z, aH2[r]); aH2[r] = fmaf(w2.w, hv.w, aH2[r]);
            }
        }
        #pragma unroll
        for (int r = 0; r < ROWS; ++r) {
            float rg = sigm(aI0[r] + aH0[r]);
            float zg = sigm(aI1[r] + aH1[r]);
            float ng = tanh_f(aI2[r] + rg * aH2[r]);
            float hold = h_s[cur][r][j];
            h_s[cur ^ 1][r][j] = ng + zg * (hold - ng);   // (1-z)n + z h
        }
        __syncthreads();

        // ---------- phase B: projection p_new = h_new @ W_proj^T + b ----------
        const int nx = cur ^ 1;
        float pa[ROWS / 2];
        #pragma unroll
        for (int ri = 0; ri < ROWS / 2; ++ri) pa[ri] = bp;
        for (int k = 0; k < HID / 4; ++k) {
            float4 w = wp[k];
            #pragma unroll
            for (int ri = 0; ri < ROWS / 2; ++ri) {
                int r = rh * (ROWS / 2) + ri;
                float4 hv = *(const float4*)&h_s[nx][r][4 * k];  // broadcast
                pa[ri] = fmaf(w.x, hv.x, pa[ri]); pa[ri] = fmaf(w.y, hv.y, pa[ri]);
                pa[ri] = fmaf(w.z, hv.z, pa[ri]); pa[ri] = fmaf(w.w, hv.w, pa[ri]);
            }
        }
        float* orow = out + (size_t)(s + 1) * B_SZ * LAT;
        #pragma unroll
        for (int ri = 0; ri < ROWS / 2; ++ri) {
            int r = rh * (ROWS / 2) + ri;
            x_s[r][o] = pa[ri];
            orow[(size_t)(row0 + r) * LAT + o] = pa[ri];
        }
        cur = nx;
        __syncthreads();
    }
}

extern "C" void kernel_launch(void* const* d_in, const int* in_sizes, int n_in,
                              void* d_out, int out_size, void* d_ws, size_t ws_size,
                              hipStream_t stream)
{
    const float* p0   = (const float*)d_in[0];
    const float* latv = (const float*)d_in[1];
    const float* lonv = (const float*)d_in[2];
    const float* W_ih = (const float*)d_in[3];
    const float* W_hh = (const float*)d_in[4];
    const float* b_ih = (const float*)d_in[5];
    const float* b_hh = (const float*)d_in[6];
    const float* W_pr = (const float*)d_in[7];
    const float* b_pr = (const float*)d_in[8];
    float* out = (float*)d_out;

    const int n_steps = out_size / (B_SZ * LAT) - 1;   // 100

    hipLaunchKernelGGL(gru_roll_kernel, dim3(NBLK), dim3(NTHR), 0, stream,
                       p0, latv, lonv, W_ih, W_hh, b_ih, b_hh, W_pr, b_pr,
                       out, n_steps);
}

// Round 2
// 10181.554 us; speedup vs baseline: 3.4407x; 3.4407x over previous
//
#include <hip/hip_runtime.h>
#include <math.h>

// GRU rollout, restructured: hidden-dim split across wgs, weights LDS-resident,
// per-step global sync via kernel relaunch (101 launches in the graph).
//
// Fusions (exact algebra, all fp32):
//   p_{s-1} = h_{s-1} @ Wp^T + bp  (s>=2)   =>  x_s = [p_{s-1}, lat, lon]
//   gi = x_s @ Wih^T + b_ih = h_{s-1} @ Wf^T + (bp-term + b_ih + lat*c1 + lon*c2)
//        where Wf = Wih[:, :256] @ Wp   (precomputed)
//   r,z: sigma(gi+gh) -> combined row Wc_rz = Wf_rz + Whh_rz
//   n  : tanh(gi_n + r * gh_n) -> Wf_n and Whh_n kept separate
// Per hidden unit: 4 K=512 dots. Plus 2 proj rows per wg for the output.
// Step s==1 uses the true x_1=[p0,lat,lon] via a precomputed gi1 = p0@Wih^T+... .

#define B_SZ   2048
#define LAT    256
#define HID    512
#define NTHR   512
#define NWG    512          // 4 groups x 128 wgs
#define HSTR   (HID * B_SZ) // one h buffer, floats

__device__ __forceinline__ float sigm(float x) {
    return 1.0f / (1.0f + __expf(-x));
}
__device__ __forceinline__ float tanh_f(float x) {
    float e = __expf(-2.0f * fabsf(x));
    float t = (1.0f - e) / (1.0f + e);
    return copysignf(t, x);
}

// ---------------- precompute: Wc[512 units][4][512] ----------------
// rows per unit u: [0]=Wf_r+Whh_r, [1]=Wf_z+Whh_z, [2]=Wf_n, [3]=Whh_n
__global__ __launch_bounds__(512) void k_wf(
    const float* __restrict__ W_ih, const float* __restrict__ W_hh,
    const float* __restrict__ W_pr, float* __restrict__ Wc)
{
    const int u = blockIdx.x;     // hidden unit
    const int k = threadIdx.x;    // output column
    __shared__ float wih_s[3][256];
    for (int i = threadIdx.x; i < 3 * 256; i += 512) {
        int j = i >> 8, o = i & 255;
        wih_s[j][o] = W_ih[(size_t)(j * HID + u) * 258 + o];
    }
    __syncthreads();
    float fr = 0.f, fz = 0.f, fn = 0.f;
    for (int o = 0; o < 256; ++o) {
        float wp = W_pr[(size_t)o * HID + k];
        fr = fmaf(wih_s[0][o], wp, fr);
        fz = fmaf(wih_s[1][o], wp, fz);
        fn = fmaf(wih_s[2][o], wp, fn);
    }
    float* dst = Wc + (size_t)u * 4 * HID;
    dst[0 * HID + k] = fr + W_hh[(size_t)u * HID + k];
    dst[1 * HID + k] = fz + W_hh[(size_t)(HID + u) * HID + k];
    dst[2 * HID + k] = fn;
    dst[3 * HID + k] = W_hh[(size_t)(2 * HID + u) * HID + k];
}

// ---------------- precompute: Bias[512][12] ----------------
// [0]Br(+bhh) [1]c1r [2]c2r [3]Bz(+bhh) [4]c1z [5]c2z
// [6]Bn_i     [7]c1n [8]c2n [9]bhh_n [10]bhh_r [11]bhh_z
__global__ __launch_bounds__(512) void k_bias(
    const float* __restrict__ W_ih, const float* __restrict__ b_ih,
    const float* __restrict__ b_hh, const float* __restrict__ b_pr,
    float* __restrict__ Bias)
{
    const int u = threadIdx.x;
    float dr = 0.f, dz = 0.f, dn = 0.f;
    for (int o = 0; o < 256; ++o) {
        float bo = b_pr[o];
        dr = fmaf(bo, W_ih[(size_t)u * 258 + o], dr);
        dz = fmaf(bo, W_ih[(size_t)(HID + u) * 258 + o], dz);
        dn = fmaf(bo, W_ih[(size_t)(2 * HID + u) * 258 + o], dn);
    }
    float* b = Bias + u * 12;
    b[0]  = b_ih[u] + b_hh[u] + dr;
    b[1]  = W_ih[(size_t)u * 258 + 256];
    b[2]  = W_ih[(size_t)u * 258 + 257];
    b[3]  = b_ih[HID + u] + b_hh[HID + u] + dz;
    b[4]  = W_ih[(size_t)(HID + u) * 258 + 256];
    b[5]  = W_ih[(size_t)(HID + u) * 258 + 257];
    b[6]  = b_ih[2 * HID + u] + dn;
    b[7]  = W_ih[(size_t)(2 * HID + u) * 258 + 256];
    b[8]  = W_ih[(size_t)(2 * HID + u) * 258 + 257];
    b[9]  = b_hh[2 * HID + u];
    b[10] = b_hh[u];
    b[11] = b_hh[HID + u];
}

// ---------------- precompute: gi1_T[1536][2048] = x1 @ Wih^T + b_ih; out[0]=p0
__global__ __launch_bounds__(512) void k_gi1(
    const float* __restrict__ p0, const float* __restrict__ latv,
    const float* __restrict__ lonv, const float* __restrict__ W_ih,
    const float* __restrict__ b_ih, float* __restrict__ gi1T,
    float* __restrict__ out)
{
    const int rb = blockIdx.x;            // 256 blocks x 8 rows
    const int t  = threadIdx.x;
    __shared__ float p0s[8][256];
    __shared__ float lat_s[8], lon_s[8];
    for (int i = t; i < 8 * 256; i += 512) {
        int r = i >> 8, o = i & 255;
        float v = p0[(size_t)(rb * 8 + r) * LAT + o];
        p0s[r][o] = v;
        out[(size_t)(rb * 8 + r) * LAT + o] = v;   // out[0] = p0
    }
    if (t < 8) { lat_s[t] = latv[rb * 8 + t]; lon_s[t] = lonv[rb * 8 + t]; }
    __syncthreads();

    for (int gg = 0; gg < 3; ++gg) {
        const int grow = t + gg * 512;
        const float* wr = W_ih + (size_t)grow * 258;
        float acc[8];
        float bi = b_ih[grow];
        #pragma unroll
        for (int r = 0; r < 8; ++r) acc[r] = bi;
        for (int o = 0; o < 256; ++o) {
            float wv = wr[o];
            #pragma unroll
            for (int r = 0; r < 8; ++r) acc[r] = fmaf(wv, p0s[r][o], acc[r]);
        }
        float c1 = wr[256], c2 = wr[257];
        #pragma unroll
        for (int r = 0; r < 8; ++r) {
            acc[r] = fmaf(lat_s[r], c1, acc[r]);
            acc[r] = fmaf(lon_s[r], c2, acc[r]);
            gi1T[(size_t)grow * B_SZ + rb * 8 + r] = acc[r];
        }
    }
}

// ---------------- main step kernel (launched once per time step) ----------------
__global__ __launch_bounds__(NTHR, 4) void k_step(
    const float* __restrict__ Wc, const float* __restrict__ Bias,
    const float* __restrict__ W_pr, const float* __restrict__ b_pr,
    const float* __restrict__ gi1T, const float* __restrict__ latv,
    const float* __restrict__ lonv, float* __restrict__ hT,
    float* __restrict__ out, int s, int ns)
{
    const int gid = blockIdx.x;
    const int g   = (gid & 7) >> 1;                 // batch group 0..3 (XCD pair)
    const int w   = ((gid >> 3) << 1) | (gid & 1);  // wg-in-group 0..127
    const int u0  = w * 4;                          // 4 hidden units
    const int o0  = w * 2;                          // 2 proj columns
    const int t   = threadIdx.x;
    const int row = g * 512 + t;                    // global batch row

    __shared__ float wc[4][4][HID];    // 32 KB
    __shared__ float wp_s[2][HID];     // 4 KB
    __shared__ float bias_s[4][12];

    {
        const float4* src = (const float4*)(Wc + (size_t)u0 * 4 * HID);
        float4* dst = (float4*)wc;
        for (int i = t; i < 4 * 4 * HID / 4; i += NTHR) dst[i] = src[i];
        const float4* srcp = (const float4*)(W_pr + (size_t)o0 * HID);
        float4* dstp = (float4*)wp_s;
        for (int i = t; i < 2 * HID / 4; i += NTHR) dstp[i] = srcp[i];
        if (t < 48) ((float*)bias_s)[t] = Bias[u0 * 12 + t];
    }
    __syncthreads();

    const float* hcur = hT + (size_t)((s - 1) & 1) * HSTR;
    float*       hnxt = hT + (size_t)(s & 1) * HSTR;

    float a[18];
    #pragma unroll
    for (int i = 0; i < 18; ++i) a[i] = 0.f;

    if (s >= 2) {
        const float* hrow = hcur + row;
        #pragma unroll 4
        for (int k = 0; k < HID; ++k) {
            float hv = hrow[(size_t)k * B_SZ];
            #pragma unroll
            for (int u = 0; u < 4; ++u) {
                a[u * 4 + 0] = fmaf(wc[u][0][k], hv, a[u * 4 + 0]);
                a[u * 4 + 1] = fmaf(wc[u][1][k], hv, a[u * 4 + 1]);
                a[u * 4 + 2] = fmaf(wc[u][2][k], hv, a[u * 4 + 2]);
                a[u * 4 + 3] = fmaf(wc[u][3][k], hv, a[u * 4 + 3]);
            }
            a[16] = fmaf(wp_s[0][k], hv, a[16]);
            a[17] = fmaf(wp_s[1][k], hv, a[17]);
        }
    }

    // ---- gates -> h_s ----
    if (s <= ns) {
        const float lt = latv[row], ln = lonv[row];
        #pragma unroll
        for (int u = 0; u < 4; ++u) {
            float pre_r, pre_z, i_n, h_n, hold;
            if (s == 1) {
                pre_r = gi1T[(size_t)(u0 + u) * B_SZ + row] + bias_s[u][10];
                pre_z = gi1T[(size_t)(HID + u0 + u) * B_SZ + row] + bias_s[u][11];
                i_n   = gi1T[(size_t)(2 * HID + u0 + u) * B_SZ + row];
                h_n   = bias_s[u][9];
                hold  = 0.f;
            } else {
                pre_r = a[u * 4 + 0] + bias_s[u][0] + lt * bias_s[u][1] + ln * bias_s[u][2];
                pre_z = a[u * 4 + 1] + bias_s[u][3] + lt * bias_s[u][4] + ln * bias_s[u][5];
                i_n   = a[u * 4 + 2] + bias_s[u][6] + lt * bias_s[u][7] + ln * bias_s[u][8];
                h_n   = a[u * 4 + 3] + bias_s[u][9];
                hold  = hcur[(size_t)(u0 + u) * B_SZ + row];
            }
            float r = sigm(pre_r);
            float z = sigm(pre_z);
            float n = tanh_f(fmaf(r, h_n, i_n));
            hnxt[(size_t)(u0 + u) * B_SZ + row] = n + z * (hold - n);
        }
    }

    // ---- output p_{s-1} (computed from the same h_{s-1} pass) ----
    if (s >= 2) {
        float* orow = out + (size_t)(s - 1) * B_SZ * LAT + (size_t)row * LAT;
        orow[o0]     = a[16] + b_pr[o0];
        orow[o0 + 1] = a[17] + b_pr[o0 + 1];
    }
}

extern "C" void kernel_launch(void* const* d_in, const int* in_sizes, int n_in,
                              void* d_out, int out_size, void* d_ws, size_t ws_size,
                              hipStream_t stream)
{
    const float* p0   = (const float*)d_in[0];
    const float* latv = (const float*)d_in[1];
    const float* lonv = (const float*)d_in[2];
    const float* W_ih = (const float*)d_in[3];
    const float* W_hh = (const float*)d_in[4];
    const float* b_ih = (const float*)d_in[5];
    const float* b_hh = (const float*)d_in[6];
    const float* W_pr = (const float*)d_in[7];
    const float* b_pr = (const float*)d_in[8];
    float* out = (float*)d_out;

    const int NS = out_size / (B_SZ * LAT) - 1;   // 100

    // workspace layout (floats)
    float* hT   = (float*)d_ws;                   // 2 * 512 * 2048
    float* gi1T = hT + 2 * HSTR;                  // 1536 * 2048
    float* Wc   = gi1T + 3 * HID * B_SZ;          // 512 * 4 * 512
    float* Bias = Wc + (size_t)HID * 4 * HID;     // 512 * 12

    hipLaunchKernelGGL(k_wf,   dim3(HID), dim3(512), 0, stream, W_ih, W_hh, W_pr, Wc);
    hipLaunchKernelGGL(k_bias, dim3(1),   dim3(512), 0, stream, W_ih, b_ih, b_hh, b_pr, Bias);
    hipLaunchKernelGGL(k_gi1,  dim3(256), dim3(512), 0, stream, p0, latv, lonv, W_ih, b_ih, gi1T, out);

    for (int s = 1; s <= NS + 1; ++s) {
        hipLaunchKernelGGL(k_step, dim3(NWG), dim3(NTHR), 0, stream,
                           Wc, Bias, W_pr, b_pr, gi1T, latv, lonv, hT, out, s, NS);
    }
}